// Round 5
// baseline (371.022 us; speedup 1.0000x reference)
//
#include <hip/hip_runtime.h>
#include <math.h>

// Problem constants (from reference)
#define NN 50000
#define EE 800000
#define NBK 196    // node buckets (256 nodes each): ceil(50000/256)
#define EPB 4096   // edges per pass-A block: ceil(800000/4096) = 196 blocks

typedef short v8s __attribute__((ext_vector_type(8)));
typedef float v4f __attribute__((ext_vector_type(4)));

__device__ __forceinline__ ushort f2bf(float f) {
    uint u = __float_as_uint(f);
    uint r = (u + 0x7fffu + ((u >> 16) & 1u)) >> 16;
    return (ushort)r;
}
__device__ __forceinline__ float bf2f(ushort h) {
    return __uint_as_float(((uint)h) << 16);
}
// leaky_relu(x,0.2) = 0.6x + 0.4|x|
__device__ __forceinline__ float lrelu(float x) {
    return fmaf(0.4f, fabsf(x), 0.6f * x);
}

// async global->LDS, 16B per lane (dest = wave-uniform base + lane*16)
__device__ __forceinline__ void gld_lds16(const void* g, void* l) {
    __builtin_amdgcn_global_load_lds(
        (const __attribute__((address_space(1))) void*)g,
        (__attribute__((address_space(3))) void*)l, 16, 0, 0);
}

// DPP partial reductions (no LDS pipe).
template <int CTRL>
__device__ __forceinline__ float dppadd(float x) {
    int y = __builtin_amdgcn_update_dpp(0, __float_as_int(x), CTRL, 0xf, 0xf, true);
    return x + __int_as_float(y);
}
__device__ __forceinline__ float sum4(float x) {   // sum within aligned 4-groups
    x = dppadd<0xB1>(x);    // quad_perm xor1
    x = dppadd<0x4E>(x);    // quad_perm xor2
    return x;
}
__device__ __forceinline__ float sum8(float x) {   // sum within aligned 8-groups
    x = dppadd<0xB1>(x);
    x = dppadd<0x4E>(x);
    x = dppadd<0x141>(x);   // row_half_mirror
    return x;
}
__device__ __forceinline__ float sum16(float x) {  // sum within aligned 16-rows
    x = sum8(x);
    x = dppadd<0x140>(x);   // row_mirror
    return x;
}
__device__ __forceinline__ float expclamp(float t) {
    return __expf(fminf(fmaxf(t, -60.f), 80.f));
}

// ---------------------------------------------------------------------------
// Bucketed CSR build — no per-node global atomics, no random global writes.
// ---------------------------------------------------------------------------
__global__ __launch_bounds__(256) void k_bktcnt(const int* __restrict__ edst,
                                                int* __restrict__ bcnt) {
    __shared__ int h[NBK];
    int t = threadIdx.x;
    if (t < NBK) h[t] = 0;
    __syncthreads();
    int eb = blockIdx.x * EPB;
    #pragma unroll
    for (int k = 0; k < EPB / 256; ++k) {
        int e = eb + k * 256 + t;
        if (e < EE) atomicAdd(&h[edst[e] >> 8], 1);
    }
    __syncthreads();
    if (t < NBK && h[t]) atomicAdd(&bcnt[t], h[t]);
}

__global__ __launch_bounds__(256) void k_bscan(const int* __restrict__ bcnt,
                                               int* __restrict__ bbase,
                                               int* __restrict__ bcur) {
    __shared__ int sm[256];
    int t = threadIdx.x;
    int v = (t < NBK) ? bcnt[t] : 0;
    sm[t] = v;
    __syncthreads();
    for (int o = 1; o < 256; o <<= 1) {
        int a = (t >= o) ? sm[t - o] : 0;
        __syncthreads();
        sm[t] += a;
        __syncthreads();
    }
    if (t < NBK) { int ex = sm[t] - v; bbase[t] = ex; bcur[t] = ex; }
}

__global__ __launch_bounds__(256) void k_bktplace(const int* __restrict__ esrc,
                                                  const int* __restrict__ edst,
                                                  int* __restrict__ bcur,
                                                  uint* __restrict__ ebuf) {
    __shared__ int h[NBK];
    __shared__ int base[NBK];
    int t = threadIdx.x;
    if (t < NBK) h[t] = 0;
    __syncthreads();
    int eb = blockIdx.x * EPB;
    int pk[EPB / 256];   // (bucket<<16)|local_rank per edge
    #pragma unroll
    for (int k = 0; k < EPB / 256; ++k) {
        int e = eb + k * 256 + t;
        pk[k] = -1;
        if (e < EE) {
            int b = edst[e] >> 8;
            int r = atomicAdd(&h[b], 1);
            pk[k] = (b << 16) | r;
        }
    }
    __syncthreads();
    if (t < NBK && h[t]) base[t] = atomicAdd(&bcur[t], h[t]);
    __syncthreads();
    #pragma unroll
    for (int k = 0; k < EPB / 256; ++k) {
        int e = eb + k * 256 + t;
        if (e < EE) {
            int b = pk[k] >> 16;
            int r = pk[k] & 0xFFFF;
            uint dl = (uint)(edst[e] & 255);
            ebuf[base[b] + r] = (dl << 16) | (uint)esrc[e];
        }
    }
}

// one block per bucket: per-node degree + scan + cursor all in LDS.
__global__ __launch_bounds__(256) void k_bktfin(const uint* __restrict__ ebuf,
                                                const int* __restrict__ bbase,
                                                const int* __restrict__ bcnt,
                                                int* __restrict__ rowptr,
                                                int* __restrict__ csrc) {
    __shared__ int deg[256];
    __shared__ int sm[256];
    __shared__ int cur[256];
    const int b = blockIdx.x;
    const int t = threadIdx.x;
    const int eb = bbase[b];
    const int ec = bcnt[b];
    deg[t] = 0;
    __syncthreads();
    for (int k = t; k < ec; k += 256)
        atomicAdd(&deg[ebuf[eb + k] >> 16], 1);
    __syncthreads();
    int v = deg[t];
    sm[t] = v;
    __syncthreads();
    for (int o = 1; o < 256; o <<= 1) {
        int a = (t >= o) ? sm[t - o] : 0;
        __syncthreads();
        sm[t] += a;
        __syncthreads();
    }
    int node = b * 256 + t;
    if (node < NN) rowptr[node + 1] = eb + sm[t];
    if (node == 0) rowptr[0] = 0;
    cur[t] = sm[t] - v;   // exclusive
    __syncthreads();
    for (int k = t; k < ec; k += 256) {
        uint u = ebuf[eb + k];
        int nl = (int)(u >> 16);
        int r = atomicAdd(&cur[nl], 1);
        csrc[eb + r] = (int)(u & 0xFFFFu);
    }
}

// ---------------------------------------------------------------------------
// Weight conversion: W [128 x FOUT] fp32 -> bf16 hi/lo in MFMA-fragment order.
// ---------------------------------------------------------------------------
struct WPack {
    const float* W[8];
    ushort* Th[8];
    ushort* Tl[8];
    int fout[8];
};

__global__ __launch_bounds__(256) void k_conv_w(WPack p) {
    int wi = blockIdx.y;
    int fout = p.fout[wi];
    int total = 128 * fout;
    int i = blockIdx.x * 256 + threadIdx.x;
    if (i >= total) return;
    int k = i / fout;
    int n = i - k * fout;
    float f = p.W[wi][i];
    ushort h = f2bf(f);
    float lo = f - bf2f(h);
    int t = n >> 4, m = n & 15, c = k >> 5, quad = (k >> 3) & 3, j = k & 7;
    int flat = ((((t * 4 + c) * 4 + quad) * 16 + m) << 3) + j;
    p.Th[wi][flat] = h;
    p.Tl[wi][flat] = f2bf(lo);
}

// ---------------------------------------------------------------------------
// Fused split-bf16 MFMA GEMM + attention-dot epilogue. (round-4 structure:
// 512 thr, B staged in LDS via global_load_lds, blockIdx.y = t-slice)
// ---------------------------------------------------------------------------
template <int FOUT, int NMAT, bool CVT, int TS>
__global__ __launch_bounds__(512) void k_gemm_fused(
    const float* __restrict__ Xf,
    const ushort* __restrict__ Xh, const ushort* __restrict__ Xl,
    const ushort* __restrict__ T0h, const ushort* __restrict__ T0l, const float* __restrict__ B0,
    const ushort* __restrict__ T1h, const ushort* __restrict__ T1l, const float* __restrict__ B1,
    const ushort* __restrict__ T2h, const ushort* __restrict__ T2l,
    const float* __restrict__ ATT, float* __restrict__ DL, float* __restrict__ DR,
    ushort* __restrict__ O0b, float* __restrict__ O1, float* __restrict__ O2)
{
    constexpr int CH = TS * 2048;                 // ushorts per staged chunk
    __shared__ __align__(16) ushort Bs[NMAT * 2 * CH];

    const int tid  = threadIdx.x;
    const int lane = tid & 63;
    const int wid  = tid >> 6;                    // 0..7
    const int m    = lane & 15;
    const int quad = lane >> 4;
    const int row0 = blockIdx.x * 128 + wid * 16;
    const int t0   = blockIdx.y * TS;

    // ---- stage B slice into LDS (one 8KB chunk per table) ----
    {
        const ushort* tbls[6] = {T0h, T0l, T1h, T1l, T2h, T2l};
        #pragma unroll
        for (int k = 0; k < 2 * NMAT; ++k) {
            gld_lds16(tbls[k] + (size_t)t0 * 2048 + (size_t)tid * 8,
                      &Bs[k * CH + tid * 8]);
        }
    }

    // ---- A fragments (per-wave rows) ----
    v8s ah[4], al[4];
    {
        int arow = row0 + m;
        if (arow > NN - 1) arow = NN - 1;
        #pragma unroll
        for (int c = 0; c < 4; ++c) {
            size_t off = (size_t)arow * 128 + c * 32 + quad * 8;
            if constexpr (CVT) {
                float4 f0 = *(const float4*)(Xf + off);
                float4 f1 = *(const float4*)(Xf + off + 4);
                const float fe[8] = {f0.x, f0.y, f0.z, f0.w, f1.x, f1.y, f1.z, f1.w};
                #pragma unroll
                for (int e = 0; e < 8; ++e) {
                    ushort h = f2bf(fe[e]);
                    float lo = fe[e] - bf2f(h);
                    ah[c][e] = (short)h;
                    al[c][e] = (short)(__float_as_uint(lo) >> 16);  // truncate lo
                }
            } else {
                ah[c] = *(const v8s*)(Xh + off);
                al[c] = *(const v8s*)(Xl + off);
            }
        }
    }

    __syncthreads();   // drains global_load_lds (vmcnt) + orders LDS

    float dp0[4] = {0.f, 0.f, 0.f, 0.f};
    float dp1[4] = {0.f, 0.f, 0.f, 0.f};

    #pragma unroll
    for (int tt = 0; tt < TS; ++tt) {
        const int t = t0 + tt;
        v4f a0 = {0.f, 0.f, 0.f, 0.f};
        v4f a1 = {0.f, 0.f, 0.f, 0.f};
        v4f a2 = {0.f, 0.f, 0.f, 0.f};
        #pragma unroll
        for (int c = 0; c < 4; ++c) {
            const int fo = tt * 2048 + (c * 4 + quad) * 128 + m * 8;
            v8s b0h = *(const v8s*)&Bs[0 * CH + fo];
            v8s b0l = *(const v8s*)&Bs[1 * CH + fo];
            v8s b1h = *(const v8s*)&Bs[2 * CH + fo];
            v8s b1l = *(const v8s*)&Bs[3 * CH + fo];
            a0 = __builtin_amdgcn_mfma_f32_16x16x32_bf16(al[c], b0h, a0, 0, 0, 0);
            a1 = __builtin_amdgcn_mfma_f32_16x16x32_bf16(al[c], b1h, a1, 0, 0, 0);
            a0 = __builtin_amdgcn_mfma_f32_16x16x32_bf16(ah[c], b0l, a0, 0, 0, 0);
            a1 = __builtin_amdgcn_mfma_f32_16x16x32_bf16(ah[c], b1l, a1, 0, 0, 0);
            a0 = __builtin_amdgcn_mfma_f32_16x16x32_bf16(ah[c], b0h, a0, 0, 0, 0);
            a1 = __builtin_amdgcn_mfma_f32_16x16x32_bf16(ah[c], b1h, a1, 0, 0, 0);
            if constexpr (NMAT == 3) {
                v8s b2h = *(const v8s*)&Bs[4 * CH + fo];
                v8s b2l = *(const v8s*)&Bs[5 * CH + fo];
                a2 = __builtin_amdgcn_mfma_f32_16x16x32_bf16(al[c], b2h, a2, 0, 0, 0);
                a2 = __builtin_amdgcn_mfma_f32_16x16x32_bf16(ah[c], b2l, a2, 0, 0, 0);
                a2 = __builtin_amdgcn_mfma_f32_16x16x32_bf16(ah[c], b2h, a2, 0, 0, 0);
            }
        }
        const int col = t * 16 + m;
        const float bad0 = B0[col];
        const float bad1 = B1[col];
        const float attc = ATT[col];
        #pragma unroll
        for (int j = 0; j < 4; ++j) {
            float o0v = a0[j] + bad0;
            float o1v = a1[j] + bad1;
            dp0[j] = fmaf(attc, o0v, dp0[j]);
            dp1[j] = fmaf(attc, o1v, dp1[j]);
            int r = row0 + quad * 4 + j;
            if (r < NN) {
                O0b[(size_t)r * FOUT + col] = f2bf(o0v);
                O1[(size_t)r * FOUT + col] = o1v;
                if constexpr (NMAT == 3) O2[(size_t)r * FOUT + col] = a2[j];
            }
        }
        if constexpr (FOUT == 128) {
            if ((t & 1) == 1) {   // head h = t>>1 complete -> reduce + store
                const int h = t >> 1;
                #pragma unroll
                for (int j = 0; j < 4; ++j) {
                    float s0 = sum16(dp0[j]);
                    float s1 = sum16(dp1[j]);
                    int r = row0 + quad * 4 + j;
                    if (m == 0 && r < NN) {
                        DL[(size_t)r * 4 + h] = 0.6f * s0;
                        DR[(size_t)r * 4 + h] = 0.6f * s1;
                    }
                    dp0[j] = 0.f;
                    dp1[j] = 0.f;
                }
            }
        }
    }
    if constexpr (FOUT == 64) {   // head spans all 4 t -> partial, atomic
        #pragma unroll
        for (int j = 0; j < 4; ++j) {
            float s0 = sum16(dp0[j]);
            float s1 = sum16(dp1[j]);
            int r = row0 + quad * 4 + j;
            if (m == 0 && r < NN) {
                atomicAdd(&DL[r], 0.6f * s0);
                atomicAdd(&DR[r], 0.6f * s1);
            }
        }
    }
}

// ---------------------------------------------------------------------------
// Aggregation layers 0/1 — 16 lanes/edge, 8 channels/lane (uint4 = 16B/lane),
// 4 edges per wave-pass, 8 edges per loop iter (2 gathers in flight).
//   lane: q = lane>>4 (edge quarter), jj = lane&15 (channels 8jj..8jj+7),
//         head = jj>>2 (4 lanes per head).
//   logit = quadsum(0.4*att_c*|xl_c+xr_c|) + DL[src,h] + DR[n,h]
// Final: cross-quarter combine via shfl_xor(16|32); q==0 lanes do epilogue.
// ---------------------------------------------------------------------------
__global__ __launch_bounds__(256) void k_agg01(const ushort* __restrict__ XLb,
                                               const float4* __restrict__ XR4,
                                               const float4* __restrict__ RES4,
                                               const float* __restrict__ att,
                                               const float* __restrict__ bias,
                                               const float* __restrict__ DL,
                                               const float* __restrict__ DR,
                                               const int* __restrict__ rowptr,
                                               const int* __restrict__ csrc,
                                               ushort* __restrict__ Hh,
                                               ushort* __restrict__ Hl) {
    const int lane = threadIdx.x & 63;
    const int wid = threadIdx.x >> 6;
    const int n = blockIdx.x * 4 + wid;
    if (n >= NN) return;
    const int beg = rowptr[n];
    const int end = rowptr[n + 1];
    const int q = lane >> 4;
    const uint jj = lane & 15;
    const uint head = jj >> 2;

    const float4 xrA = XR4[(uint)n * 32u + 2u * jj];
    const float4 xrB = XR4[(uint)n * 32u + 2u * jj + 1u];
    float4 atA = ((const float4*)att)[2u * jj];
    float4 atB = ((const float4*)att)[2u * jj + 1u];
    atA.x *= 0.4f; atA.y *= 0.4f; atA.z *= 0.4f; atA.w *= 0.4f;
    atB.x *= 0.4f; atB.y *= 0.4f; atB.z *= 0.4f; atB.w *= 0.4f;
    const float dRn = DR[(uint)n * 4u + head];
    float s0_ = 0.f, s1_ = 0.f, s2_ = 0.f, s3_ = 0.f;
    float s4_ = 0.f, s5_ = 0.f, s6_ = 0.f, s7_ = 0.f;
    float d = 0.f;
    const int e1 = end - 1;

#define PROC01(U, DLV, II) {                                   \
    float v0 = __uint_as_float((U).x << 16);                   \
    float v1 = __uint_as_float((U).x & 0xFFFF0000u);           \
    float v2 = __uint_as_float((U).y << 16);                   \
    float v3 = __uint_as_float((U).y & 0xFFFF0000u);           \
    float v4 = __uint_as_float((U).z << 16);                   \
    float v5 = __uint_as_float((U).z & 0xFFFF0000u);           \
    float v6 = __uint_as_float((U).w << 16);                   \
    float v7 = __uint_as_float((U).w & 0xFFFF0000u);           \
    float t =      atA.x * fabsf(v0 + xrA.x);                  \
    t = fmaf(atA.y, fabsf(v1 + xrA.y), t);                     \
    t = fmaf(atA.z, fabsf(v2 + xrA.z), t);                     \
    t = fmaf(atA.w, fabsf(v3 + xrA.w), t);                     \
    t = fmaf(atB.x, fabsf(v4 + xrB.x), t);                     \
    t = fmaf(atB.y, fabsf(v5 + xrB.y), t);                     \
    t = fmaf(atB.z, fabsf(v6 + xrB.z), t);                     \
    t = fmaf(atB.w, fabsf(v7 + xrB.w), t);                     \
    t = sum4(t);                                               \
    float p = expclamp(t + (DLV) + dRn);                       \
    if ((II) >= end) p = 0.f;                                  \
    d += p;                                                    \
    s0_ = fmaf(p, v0, s0_); s1_ = fmaf(p, v1, s1_);            \
    s2_ = fmaf(p, v2, s2_); s3_ = fmaf(p, v3, s3_);            \
    s4_ = fmaf(p, v4, s4_); s5_ = fmaf(p, v5, s5_);            \
    s6_ = fmaf(p, v6, s6_); s7_ = fmaf(p, v7, s7_); }

    for (int i = beg; i < end; i += 8) {
        int i0 = i + q;
        int i1 = i + 4 + q;
        uint sa = (uint)csrc[min(i0, e1)];
        uint sb = (uint)csrc[min(i1, e1)];
        uint4 Ua = *(const uint4*)(XLb + sa * 128u + 8u * jj);
        float da_ = DL[sa * 4u + head];
        uint4 Ub = *(const uint4*)(XLb + sb * 128u + 8u * jj);
        float db_ = DL[sb * 4u + head];
        PROC01(Ua, da_, i0)
        PROC01(Ub, db_, i1)
    }
#undef PROC01

    d   += __shfl_xor(d, 16);   d   += __shfl_xor(d, 32);
    s0_ += __shfl_xor(s0_, 16); s0_ += __shfl_xor(s0_, 32);
    s1_ += __shfl_xor(s1_, 16); s1_ += __shfl_xor(s1_, 32);
    s2_ += __shfl_xor(s2_, 16); s2_ += __shfl_xor(s2_, 32);
    s3_ += __shfl_xor(s3_, 16); s3_ += __shfl_xor(s3_, 32);
    s4_ += __shfl_xor(s4_, 16); s4_ += __shfl_xor(s4_, 32);
    s5_ += __shfl_xor(s5_, 16); s5_ += __shfl_xor(s5_, 32);
    s6_ += __shfl_xor(s6_, 16); s6_ += __shfl_xor(s6_, 32);
    s7_ += __shfl_xor(s7_, 16); s7_ += __shfl_xor(s7_, 32);

    if (q == 0) {
        float inv = (d > 0.f) ? 1.f / d : 0.f;
        const float4 rA = RES4[(uint)n * 32u + 2u * jj];
        const float4 rB = RES4[(uint)n * 32u + 2u * jj + 1u];
        const float4 bA = ((const float4*)bias)[2u * jj];
        const float4 bB = ((const float4*)bias)[2u * jj + 1u];
        float o[8];
        o[0] = fmaf(s0_, inv, rA.x + bA.x);
        o[1] = fmaf(s1_, inv, rA.y + bA.y);
        o[2] = fmaf(s2_, inv, rA.z + bA.z);
        o[3] = fmaf(s3_, inv, rA.w + bA.w);
        o[4] = fmaf(s4_, inv, rB.x + bB.x);
        o[5] = fmaf(s5_, inv, rB.y + bB.y);
        o[6] = fmaf(s6_, inv, rB.z + bB.z);
        o[7] = fmaf(s7_, inv, rB.w + bB.w);
        v8s hh, ll;
        #pragma unroll
        for (int c = 0; c < 8; ++c) {
            float ov = o[c];
            ov = ov > 0.f ? ov : __expf(ov) - 1.f;   // ELU
            ushort h = f2bf(ov);
            hh[c] = (short)h;
            ll[c] = (short)f2bf(ov - bf2f(h));
        }
        *(v8s*)(Hh + (uint)n * 128u + 8u * jj) = hh;
        *(v8s*)(Hl + (uint)n * 128u + 8u * jj) = ll;
    }
}

// ---------------------------------------------------------------------------
// Aggregation layer 2 — F=64, H=1. 8 lanes/edge, 8 channels/lane (16B/lane),
// 8 edges per wave-pass, 16 edges per loop iter.
//   q = lane>>3 (edge octant), jj = lane&7 (channels 8jj..8jj+7).
// ---------------------------------------------------------------------------
__global__ __launch_bounds__(256) void k_agg2(const ushort* __restrict__ XLb,
                                              const float4* __restrict__ XR4,
                                              const float* __restrict__ att,
                                              const float* __restrict__ bias,
                                              const float* __restrict__ DL,
                                              const float* __restrict__ DR,
                                              const int* __restrict__ rowptr,
                                              const int* __restrict__ csrc,
                                              float* __restrict__ OUT) {
    const int lane = threadIdx.x & 63;
    const int wid = threadIdx.x >> 6;
    const int n = blockIdx.x * 4 + wid;
    if (n >= NN) return;
    const int beg = rowptr[n];
    const int end = rowptr[n + 1];
    const int q = lane >> 3;
    const uint jj = lane & 7;

    const float4 xrA = XR4[(uint)n * 16u + 2u * jj];
    const float4 xrB = XR4[(uint)n * 16u + 2u * jj + 1u];
    float4 atA = ((const float4*)att)[2u * jj];
    float4 atB = ((const float4*)att)[2u * jj + 1u];
    atA.x *= 0.4f; atA.y *= 0.4f; atA.z *= 0.4f; atA.w *= 0.4f;
    atB.x *= 0.4f; atB.y *= 0.4f; atB.z *= 0.4f; atB.w *= 0.4f;
    const float dRn = DR[n];
    float s0_ = 0.f, s1_ = 0.f, s2_ = 0.f, s3_ = 0.f;
    float s4_ = 0.f, s5_ = 0.f, s6_ = 0.f, s7_ = 0.f;
    float d = 0.f;
    const int e1 = end - 1;

#define PROC2(U, DLV, II) {                                    \
    float v0 = __uint_as_float((U).x << 16);                   \
    float v1 = __uint_as_float((U).x & 0xFFFF0000u);           \
    float v2 = __uint_as_float((U).y << 16);                   \
    float v3 = __uint_as_float((U).y & 0xFFFF0000u);           \
    float v4 = __uint_as_float((U).z << 16);                   \
    float v5 = __uint_as_float((U).z & 0xFFFF0000u);           \
    float v6 = __uint_as_float((U).w << 16);                   \
    float v7 = __uint_as_float((U).w & 0xFFFF0000u);           \
    float t =      atA.x * fabsf(v0 + xrA.x);                  \
    t = fmaf(atA.y, fabsf(v1 + xrA.y), t);                     \
    t = fmaf(atA.z, fabsf(v2 + xrA.z), t);                     \
    t = fmaf(atA.w, fabsf(v3 + xrA.w), t);                     \
    t = fmaf(atB.x, fabsf(v4 + xrB.x), t);                     \
    t = fmaf(atB.y, fabsf(v5 + xrB.y), t);                     \
    t = fmaf(atB.z, fabsf(v6 + xrB.z), t);                     \
    t = fmaf(atB.w, fabsf(v7 + xrB.w), t);                     \
    t = sum8(t);                                               \
    float p = expclamp(t + (DLV) + dRn);                       \
    if ((II) >= end) p = 0.f;                                  \
    d += p;                                                    \
    s0_ = fmaf(p, v0, s0_); s1_ = fmaf(p, v1, s1_);            \
    s2_ = fmaf(p, v2, s2_); s3_ = fmaf(p, v3, s3_);            \
    s4_ = fmaf(p, v4, s4_); s5_ = fmaf(p, v5, s5_);            \
    s6_ = fmaf(p, v6, s6_); s7_ = fmaf(p, v7, s7_); }

    for (int i = beg; i < end; i += 16) {
        int i0 = i + q;
        int i1 = i + 8 + q;
        uint sa = (uint)csrc[min(i0, e1)];
        uint sb = (uint)csrc[min(i1, e1)];
        uint4 Ua = *(const uint4*)(XLb + sa * 64u + 8u * jj);
        float da_ = DL[sa];
        uint4 Ub = *(const uint4*)(XLb + sb * 64u + 8u * jj);
        float db_ = DL[sb];
        PROC2(Ua, da_, i0)
        PROC2(Ub, db_, i1)
    }
#undef PROC2

    d   += __shfl_xor(d, 8);    d   += __shfl_xor(d, 16);   d   += __shfl_xor(d, 32);
    s0_ += __shfl_xor(s0_, 8);  s0_ += __shfl_xor(s0_, 16); s0_ += __shfl_xor(s0_, 32);
    s1_ += __shfl_xor(s1_, 8);  s1_ += __shfl_xor(s1_, 16); s1_ += __shfl_xor(s1_, 32);
    s2_ += __shfl_xor(s2_, 8);  s2_ += __shfl_xor(s2_, 16); s2_ += __shfl_xor(s2_, 32);
    s3_ += __shfl_xor(s3_, 8);  s3_ += __shfl_xor(s3_, 16); s3_ += __shfl_xor(s3_, 32);
    s4_ += __shfl_xor(s4_, 8);  s4_ += __shfl_xor(s4_, 16); s4_ += __shfl_xor(s4_, 32);
    s5_ += __shfl_xor(s5_, 8);  s5_ += __shfl_xor(s5_, 16); s5_ += __shfl_xor(s5_, 32);
    s6_ += __shfl_xor(s6_, 8);  s6_ += __shfl_xor(s6_, 16); s6_ += __shfl_xor(s6_, 32);
    s7_ += __shfl_xor(s7_, 8);  s7_ += __shfl_xor(s7_, 16); s7_ += __shfl_xor(s7_, 32);

    if (lane < 8) {
        float inv = (d > 0.f) ? 1.f / d : 0.f;
        const float4 bA = ((const float4*)bias)[2u * jj];
        const float4 bB = ((const float4*)bias)[2u * jj + 1u];
        float4 oA, oB;
        oA.x = fmaf(s0_, inv, bA.x);
        oA.y = fmaf(s1_, inv, bA.y);
        oA.z = fmaf(s2_, inv, bA.z);
        oA.w = fmaf(s3_, inv, bA.w);
        oB.x = fmaf(s4_, inv, bB.x);
        oB.y = fmaf(s5_, inv, bB.y);
        oB.z = fmaf(s6_, inv, bB.z);
        oB.w = fmaf(s7_, inv, bB.w);
        *(float4*)(OUT + (uint)n * 64u + 8u * jj) = oA;
        *(float4*)(OUT + (uint)n * 64u + 8u * jj + 4u) = oB;
    }
}

// ---------------------------------------------------------------------------
extern "C" void kernel_launch(void* const* d_in, const int* in_sizes, int n_in,
                              void* d_out, int out_size, void* d_ws, size_t ws_size,
                              hipStream_t stream) {
    const float* x    = (const float*)d_in[0];
    const int*   ei   = (const int*)d_in[1];
    const int*   esrc = ei;
    const int*   edst = ei + EE;

    const float* Wl0 = (const float*)d_in[2];
    const float* bl0 = (const float*)d_in[3];
    const float* Wr0 = (const float*)d_in[4];
    const float* br0 = (const float*)d_in[5];
    const float* at0 = (const float*)d_in[6];
    const float* b0  = (const float*)d_in[7];
    const float* rs0 = (const float*)d_in[8];
    const float* Wl1 = (const float*)d_in[9];
    const float* bl1 = (const float*)d_in[10];
    const float* Wr1 = (const float*)d_in[11];
    const float* br1 = (const float*)d_in[12];
    const float* at1 = (const float*)d_in[13];
    const float* b1  = (const float*)d_in[14];
    const float* rs1 = (const float*)d_in[15];
    const float* Wl2 = (const float*)d_in[16];
    const float* bl2 = (const float*)d_in[17];
    const float* Wr2 = (const float*)d_in[18];
    const float* br2 = (const float*)d_in[19];
    const float* at2 = (const float*)d_in[20];
    const float* b2  = (const float*)d_in[21];

    float* out = (float*)d_out;

    // --- workspace layout ---
    ushort* XLb = (ushort*)d_ws;               // [NN*128] bf16 (gather payload)
    float* XR  = (float*)(XLb + (size_t)NN * 128);    // [NN*128] fp32
    float* RES = XR + (size_t)NN * 128;               // [NN*128] fp32
    ushort* Xh = (ushort*)(RES + (size_t)NN * 128);   // [NN*128] bf16-hi (H)
    ushort* Xl_ = Xh + (size_t)NN * 128;              // [NN*128] bf16-lo (H)
    float* DLarr = (float*)(Xl_ + (size_t)NN * 128);  // [NN*4] fp32 dotL
    float* DRarr = DLarr + (size_t)NN * 4;            // [NN*4] fp32 dotR
    ushort* Wth = (ushort*)(DRarr + (size_t)NN * 4);
    const int wsz[8] = {16384, 16384, 16384, 16384, 16384, 16384, 8192, 8192};
    ushort* th[8]; ushort* tl[8];
    {
        ushort* p = Wth;
        for (int i = 0; i < 8; ++i) { th[i] = p; p += wsz[i]; }
        for (int i = 0; i < 8; ++i) { tl[i] = p; p += wsz[i]; }
    }
    int* bcnt   = (int*)(Wth + 2 * (6 * 16384 + 2 * 8192));  // 256 (memset)
    int* bbase  = bcnt + 256;                  // 256
    int* bcur   = bbase + 256;                 // 256
    int* rowptr = bcur + 256;                  // NN+1
    int* csrc   = rowptr + (NN + 1);           // EE
    uint* ebuf  = (uint*)(csrc + EE);          // EE

    // --- bucketed CSR build (graph identical across layers) ---
    hipMemsetAsync(bcnt, 0, 256 * sizeof(int), stream);
    const int ebk = (EE + EPB - 1) / EPB;      // 196
    k_bktcnt<<<ebk, 256, 0, stream>>>(edst, bcnt);
    k_bscan<<<1, 256, 0, stream>>>(bcnt, bbase, bcur);
    k_bktplace<<<ebk, 256, 0, stream>>>(esrc, edst, bcur, ebuf);
    k_bktfin<<<NBK, 256, 0, stream>>>(ebuf, bbase, bcnt, rowptr, csrc);

    // --- weight conversion ---
    WPack wp;
    const float* Ws[8] = {Wl0, Wr0, rs0, Wl1, Wr1, rs1, Wl2, Wr2};
    const int fouts[8] = {128, 128, 128, 128, 128, 128, 64, 64};
    for (int i = 0; i < 8; ++i) { wp.W[i] = Ws[i]; wp.Th[i] = th[i]; wp.Tl[i] = tl[i]; wp.fout[i] = fouts[i]; }
    k_conv_w<<<dim3(64, 8), 256, 0, stream>>>(wp);

    const int gemm_gx = (NN + 127) / 128;      // 391 row-tiles (128 rows/block)
    const int agg_grid = (NN + 3) / 4;

    // --- Layer 0 (A from fp32 x; 3 weight mats fused; grid.y = t-slice) ---
    k_gemm_fused<128, 3, true, 2><<<dim3(gemm_gx, 4), 512, 0, stream>>>(x, nullptr, nullptr,
        th[0], tl[0], bl0, th[1], tl[1], br0, th[2], tl[2], at0, DLarr, DRarr, XLb, XR, RES);
    k_agg01<<<agg_grid, 256, 0, stream>>>(XLb, (const float4*)XR, (const float4*)RES,
        at0, b0, DLarr, DRarr, rowptr, csrc, Xh, Xl_);

    // --- Layer 1 ---
    k_gemm_fused<128, 3, false, 2><<<dim3(gemm_gx, 4), 512, 0, stream>>>(nullptr, Xh, Xl_,
        th[3], tl[3], bl1, th[4], tl[4], br1, th[5], tl[5], at1, DLarr, DRarr, XLb, XR, RES);
    k_agg01<<<agg_grid, 256, 0, stream>>>(XLb, (const float4*)XR, (const float4*)RES,
        at1, b1, DLarr, DRarr, rowptr, csrc, Xh, Xl_);

    // --- Layer 2 (heads=1, C=64; dot partials via atomics into zeroed DL/DR) ---
    hipMemsetAsync(DLarr, 0, NN * sizeof(float), stream);
    hipMemsetAsync(DRarr, 0, NN * sizeof(float), stream);
    k_gemm_fused<64, 2, false, 2><<<dim3(gemm_gx, 2), 512, 0, stream>>>(nullptr, Xh, Xl_,
        th[6], tl[6], bl2, th[7], tl[7], br2, nullptr, nullptr, at2, DLarr, DRarr, XLb, XR, nullptr);
    k_agg2<<<agg_grid, 256, 0, stream>>>(XLb, (const float4*)XR, at2, b2, DLarr, DRarr, rowptr, csrc, out);
}

// Round 6
// 355.600 us; speedup vs baseline: 1.0434x; 1.0434x over previous
//
#include <hip/hip_runtime.h>
#include <math.h>

// Problem constants (from reference)
#define NN 50000
#define EE 800000
#define NBK 196    // node buckets (256 nodes each): ceil(50000/256)
#define EPB 4096   // edges per pass-A block: ceil(800000/4096) = 196 blocks

typedef short v8s __attribute__((ext_vector_type(8)));
typedef float v4f __attribute__((ext_vector_type(4)));

__device__ __forceinline__ ushort f2bf(float f) {
    uint u = __float_as_uint(f);
    uint r = (u + 0x7fffu + ((u >> 16) & 1u)) >> 16;
    return (ushort)r;
}
__device__ __forceinline__ float bf2f(ushort h) {
    return __uint_as_float(((uint)h) << 16);
}
// leaky_relu(x,0.2) = 0.6x + 0.4|x|
__device__ __forceinline__ float lrelu(float x) {
    return fmaf(0.4f, fabsf(x), 0.6f * x);
}

// async global->LDS, 16B per lane (dest = wave-uniform base + lane*16)
__device__ __forceinline__ void gld_lds16(const void* g, void* l) {
    __builtin_amdgcn_global_load_lds(
        (const __attribute__((address_space(1))) void*)g,
        (__attribute__((address_space(3))) void*)l, 16, 0, 0);
}

// DPP partial reductions (no LDS pipe).
template <int CTRL>
__device__ __forceinline__ float dppadd(float x) {
    int y = __builtin_amdgcn_update_dpp(0, __float_as_int(x), CTRL, 0xf, 0xf, true);
    return x + __int_as_float(y);
}
__device__ __forceinline__ float sum8(float x) {   // sum within aligned 8-groups
    x = dppadd<0xB1>(x);    // quad_perm xor1
    x = dppadd<0x4E>(x);    // quad_perm xor2
    x = dppadd<0x141>(x);   // row_half_mirror
    return x;
}
__device__ __forceinline__ float sum16(float x) {  // sum within aligned 16-rows
    x = sum8(x);
    x = dppadd<0x140>(x);   // row_mirror
    return x;
}
__device__ __forceinline__ float expclamp(float t) {
    return __expf(fminf(fmaxf(t, -60.f), 80.f));
}

// ---------------------------------------------------------------------------
// Bucketed CSR build — no per-node global atomics, no random global writes.
// ---------------------------------------------------------------------------
__global__ __launch_bounds__(256) void k_bktcnt(const int* __restrict__ edst,
                                                int* __restrict__ bcnt) {
    __shared__ int h[NBK];
    int t = threadIdx.x;
    if (t < NBK) h[t] = 0;
    __syncthreads();
    int eb = blockIdx.x * EPB;
    #pragma unroll
    for (int k = 0; k < EPB / 256; ++k) {
        int e = eb + k * 256 + t;
        if (e < EE) atomicAdd(&h[edst[e] >> 8], 1);
    }
    __syncthreads();
    if (t < NBK && h[t]) atomicAdd(&bcnt[t], h[t]);
}

__global__ __launch_bounds__(256) void k_bscan(const int* __restrict__ bcnt,
                                               int* __restrict__ bbase,
                                               int* __restrict__ bcur) {
    __shared__ int sm[256];
    int t = threadIdx.x;
    int v = (t < NBK) ? bcnt[t] : 0;
    sm[t] = v;
    __syncthreads();
    for (int o = 1; o < 256; o <<= 1) {
        int a = (t >= o) ? sm[t - o] : 0;
        __syncthreads();
        sm[t] += a;
        __syncthreads();
    }
    if (t < NBK) { int ex = sm[t] - v; bbase[t] = ex; bcur[t] = ex; }
}

__global__ __launch_bounds__(256) void k_bktplace(const int* __restrict__ esrc,
                                                  const int* __restrict__ edst,
                                                  int* __restrict__ bcur,
                                                  uint* __restrict__ ebuf) {
    __shared__ int h[NBK];
    __shared__ int base[NBK];
    int t = threadIdx.x;
    if (t < NBK) h[t] = 0;
    __syncthreads();
    int eb = blockIdx.x * EPB;
    int pk[EPB / 256];   // (bucket<<16)|local_rank per edge
    #pragma unroll
    for (int k = 0; k < EPB / 256; ++k) {
        int e = eb + k * 256 + t;
        pk[k] = -1;
        if (e < EE) {
            int b = edst[e] >> 8;
            int r = atomicAdd(&h[b], 1);
            pk[k] = (b << 16) | r;
        }
    }
    __syncthreads();
    if (t < NBK && h[t]) base[t] = atomicAdd(&bcur[t], h[t]);
    __syncthreads();
    #pragma unroll
    for (int k = 0; k < EPB / 256; ++k) {
        int e = eb + k * 256 + t;
        if (e < EE) {
            int b = pk[k] >> 16;
            int r = pk[k] & 0xFFFF;
            uint dl = (uint)(edst[e] & 255);
            ebuf[base[b] + r] = (dl << 16) | (uint)esrc[e];
        }
    }
}

// one block per bucket: per-node degree + scan + cursor all in LDS.
__global__ __launch_bounds__(256) void k_bktfin(const uint* __restrict__ ebuf,
                                                const int* __restrict__ bbase,
                                                const int* __restrict__ bcnt,
                                                int* __restrict__ rowptr,
                                                int* __restrict__ csrc) {
    __shared__ int deg[256];
    __shared__ int sm[256];
    __shared__ int cur[256];
    const int b = blockIdx.x;
    const int t = threadIdx.x;
    const int eb = bbase[b];
    const int ec = bcnt[b];
    deg[t] = 0;
    __syncthreads();
    for (int k = t; k < ec; k += 256)
        atomicAdd(&deg[ebuf[eb + k] >> 16], 1);
    __syncthreads();
    int v = deg[t];
    sm[t] = v;
    __syncthreads();
    for (int o = 1; o < 256; o <<= 1) {
        int a = (t >= o) ? sm[t - o] : 0;
        __syncthreads();
        sm[t] += a;
        __syncthreads();
    }
    int node = b * 256 + t;
    if (node < NN) rowptr[node + 1] = eb + sm[t];
    if (node == 0) rowptr[0] = 0;
    cur[t] = sm[t] - v;   // exclusive
    __syncthreads();
    for (int k = t; k < ec; k += 256) {
        uint u = ebuf[eb + k];
        int nl = (int)(u >> 16);
        int r = atomicAdd(&cur[nl], 1);
        csrc[eb + r] = (int)(u & 0xFFFFu);
    }
}

// ---------------------------------------------------------------------------
// Weight conversion: W [128 x FOUT] fp32 -> bf16 hi/lo in MFMA-fragment order.
// ---------------------------------------------------------------------------
struct WPack {
    const float* W[8];
    ushort* Th[8];
    ushort* Tl[8];
    int fout[8];
};

__global__ __launch_bounds__(256) void k_conv_w(WPack p) {
    int wi = blockIdx.y;
    int fout = p.fout[wi];
    int total = 128 * fout;
    int i = blockIdx.x * 256 + threadIdx.x;
    if (i >= total) return;
    int k = i / fout;
    int n = i - k * fout;
    float f = p.W[wi][i];
    ushort h = f2bf(f);
    float lo = f - bf2f(h);
    int t = n >> 4, m = n & 15, c = k >> 5, quad = (k >> 3) & 3, j = k & 7;
    int flat = ((((t * 4 + c) * 4 + quad) * 16 + m) << 3) + j;
    p.Th[wi][flat] = h;
    p.Tl[wi][flat] = f2bf(lo);
}

// ---------------------------------------------------------------------------
// Fused split-bf16 MFMA GEMM + attention-dot epilogue. (round-4 structure:
// 512 thr, B staged in LDS via global_load_lds, blockIdx.y = t-slice)
// ---------------------------------------------------------------------------
template <int FOUT, int NMAT, bool CVT, int TS>
__global__ __launch_bounds__(512) void k_gemm_fused(
    const float* __restrict__ Xf,
    const ushort* __restrict__ Xh, const ushort* __restrict__ Xl,
    const ushort* __restrict__ T0h, const ushort* __restrict__ T0l, const float* __restrict__ B0,
    const ushort* __restrict__ T1h, const ushort* __restrict__ T1l, const float* __restrict__ B1,
    const ushort* __restrict__ T2h, const ushort* __restrict__ T2l,
    const float* __restrict__ ATT, float* __restrict__ DL, float* __restrict__ DR,
    ushort* __restrict__ O0b, float* __restrict__ O1, float* __restrict__ O2)
{
    constexpr int CH = TS * 2048;                 // ushorts per staged chunk
    __shared__ __align__(16) ushort Bs[NMAT * 2 * CH];

    const int tid  = threadIdx.x;
    const int lane = tid & 63;
    const int wid  = tid >> 6;                    // 0..7
    const int m    = lane & 15;
    const int quad = lane >> 4;
    const int row0 = blockIdx.x * 128 + wid * 16;
    const int t0   = blockIdx.y * TS;

    // ---- stage B slice into LDS (one 8KB chunk per table) ----
    {
        const ushort* tbls[6] = {T0h, T0l, T1h, T1l, T2h, T2l};
        #pragma unroll
        for (int k = 0; k < 2 * NMAT; ++k) {
            gld_lds16(tbls[k] + (size_t)t0 * 2048 + (size_t)tid * 8,
                      &Bs[k * CH + tid * 8]);
        }
    }

    // ---- A fragments (per-wave rows) ----
    v8s ah[4], al[4];
    {
        int arow = row0 + m;
        if (arow > NN - 1) arow = NN - 1;
        #pragma unroll
        for (int c = 0; c < 4; ++c) {
            size_t off = (size_t)arow * 128 + c * 32 + quad * 8;
            if constexpr (CVT) {
                float4 f0 = *(const float4*)(Xf + off);
                float4 f1 = *(const float4*)(Xf + off + 4);
                const float fe[8] = {f0.x, f0.y, f0.z, f0.w, f1.x, f1.y, f1.z, f1.w};
                #pragma unroll
                for (int e = 0; e < 8; ++e) {
                    ushort h = f2bf(fe[e]);
                    float lo = fe[e] - bf2f(h);
                    ah[c][e] = (short)h;
                    al[c][e] = (short)(__float_as_uint(lo) >> 16);  // truncate lo
                }
            } else {
                ah[c] = *(const v8s*)(Xh + off);
                al[c] = *(const v8s*)(Xl + off);
            }
        }
    }

    __syncthreads();   // drains global_load_lds (vmcnt) + orders LDS

    float dp0[4] = {0.f, 0.f, 0.f, 0.f};
    float dp1[4] = {0.f, 0.f, 0.f, 0.f};

    #pragma unroll
    for (int tt = 0; tt < TS; ++tt) {
        const int t = t0 + tt;
        v4f a0 = {0.f, 0.f, 0.f, 0.f};
        v4f a1 = {0.f, 0.f, 0.f, 0.f};
        v4f a2 = {0.f, 0.f, 0.f, 0.f};
        #pragma unroll
        for (int c = 0; c < 4; ++c) {
            const int fo = tt * 2048 + (c * 4 + quad) * 128 + m * 8;
            v8s b0h = *(const v8s*)&Bs[0 * CH + fo];
            v8s b0l = *(const v8s*)&Bs[1 * CH + fo];
            v8s b1h = *(const v8s*)&Bs[2 * CH + fo];
            v8s b1l = *(const v8s*)&Bs[3 * CH + fo];
            a0 = __builtin_amdgcn_mfma_f32_16x16x32_bf16(al[c], b0h, a0, 0, 0, 0);
            a1 = __builtin_amdgcn_mfma_f32_16x16x32_bf16(al[c], b1h, a1, 0, 0, 0);
            a0 = __builtin_amdgcn_mfma_f32_16x16x32_bf16(ah[c], b0l, a0, 0, 0, 0);
            a1 = __builtin_amdgcn_mfma_f32_16x16x32_bf16(ah[c], b1l, a1, 0, 0, 0);
            a0 = __builtin_amdgcn_mfma_f32_16x16x32_bf16(ah[c], b0h, a0, 0, 0, 0);
            a1 = __builtin_amdgcn_mfma_f32_16x16x32_bf16(ah[c], b1h, a1, 0, 0, 0);
            if constexpr (NMAT == 3) {
                v8s b2h = *(const v8s*)&Bs[4 * CH + fo];
                v8s b2l = *(const v8s*)&Bs[5 * CH + fo];
                a2 = __builtin_amdgcn_mfma_f32_16x16x32_bf16(al[c], b2h, a2, 0, 0, 0);
                a2 = __builtin_amdgcn_mfma_f32_16x16x32_bf16(ah[c], b2l, a2, 0, 0, 0);
                a2 = __builtin_amdgcn_mfma_f32_16x16x32_bf16(ah[c], b2h, a2, 0, 0, 0);
            }
        }
        const int col = t * 16 + m;
        const float bad0 = B0[col];
        const float bad1 = B1[col];
        const float attc = ATT[col];
        #pragma unroll
        for (int j = 0; j < 4; ++j) {
            float o0v = a0[j] + bad0;
            float o1v = a1[j] + bad1;
            dp0[j] = fmaf(attc, o0v, dp0[j]);
            dp1[j] = fmaf(attc, o1v, dp1[j]);
            int r = row0 + quad * 4 + j;
            if (r < NN) {
                O0b[(size_t)r * FOUT + col] = f2bf(o0v);
                O1[(size_t)r * FOUT + col] = o1v;
                if constexpr (NMAT == 3) O2[(size_t)r * FOUT + col] = a2[j];
            }
        }
        if constexpr (FOUT == 128) {
            if ((t & 1) == 1) {   // head h = t>>1 complete -> reduce + store
                const int h = t >> 1;
                #pragma unroll
                for (int j = 0; j < 4; ++j) {
                    float s0 = sum16(dp0[j]);
                    float s1 = sum16(dp1[j]);
                    int r = row0 + quad * 4 + j;
                    if (m == 0 && r < NN) {
                        DL[(size_t)r * 4 + h] = 0.6f * s0;
                        DR[(size_t)r * 4 + h] = 0.6f * s1;
                    }
                    dp0[j] = 0.f;
                    dp1[j] = 0.f;
                }
            }
        }
    }
    if constexpr (FOUT == 64) {   // head spans all 4 t -> partial, atomic
        #pragma unroll
        for (int j = 0; j < 4; ++j) {
            float s0 = sum16(dp0[j]);
            float s1 = sum16(dp1[j]);
            int r = row0 + quad * 4 + j;
            if (m == 0 && r < NN) {
                atomicAdd(&DL[r], 0.6f * s0);
                atomicAdd(&DR[r], 0.6f * s1);
            }
        }
    }
}

// ---------------------------------------------------------------------------
// Aggregation layers 0/1 — 32 lanes/edge, 4 channels/lane (round-4 shape),
// 2-stage software pipeline: packet k+1's 12 loads issued before computing
// packet k. Unified masked loop (no serial tail). uint addressing.
//   logit = sum8(0.4*att_c*|xl_c+xr_c|) + DL[src,h] + DR[n,h]
// ---------------------------------------------------------------------------
__global__ __launch_bounds__(256) void k_agg01(const ushort* __restrict__ XLb,
                                               const float4* __restrict__ XR4,
                                               const float4* __restrict__ RES4,
                                               const float* __restrict__ att,
                                               const float* __restrict__ bias,
                                               const float* __restrict__ DL,
                                               const float* __restrict__ DR,
                                               const int* __restrict__ rowptr,
                                               const int* __restrict__ csrc,
                                               ushort* __restrict__ Hh,
                                               ushort* __restrict__ Hl) {
    const int lane = threadIdx.x & 63;
    const int wid = threadIdx.x >> 6;
    const int n = blockIdx.x * 4 + wid;
    if (n >= NN) return;
    const int beg = rowptr[n];
    const int end = rowptr[n + 1];
    const int e1 = end - 1;
    const int half = lane >> 5;
    const uint j = lane & 31;
    const uint head = j >> 3;

    const float4 xr = XR4[(uint)n * 32u + j];
    float4 at = ((const float4*)att)[j];
    at.x *= 0.4f; at.y *= 0.4f; at.z *= 0.4f; at.w *= 0.4f;
    const float dRn = DR[(uint)n * 4u + head];
    float4 s = {0.f, 0.f, 0.f, 0.f};
    float d = 0.f;

#define GL01(I, U0, U1, U2, U3, D0, D1, D2, D3) {              \
    uint sa = (uint)csrc[min((I) + half, e1)];                 \
    uint sb = (uint)csrc[min((I) + 2 + half, e1)];             \
    uint sc = (uint)csrc[min((I) + 4 + half, e1)];             \
    uint sd = (uint)csrc[min((I) + 6 + half, e1)];             \
    U0 = *(const ushort4*)(XLb + sa * 128u + 4u * j);          \
    U1 = *(const ushort4*)(XLb + sb * 128u + 4u * j);          \
    U2 = *(const ushort4*)(XLb + sc * 128u + 4u * j);          \
    U3 = *(const ushort4*)(XLb + sd * 128u + 4u * j);          \
    D0 = DL[sa * 4u + head];                                   \
    D1 = DL[sb * 4u + head];                                   \
    D2 = DL[sc * 4u + head];                                   \
    D3 = DL[sd * 4u + head]; }

#define EDGE01(U, DLV, II) {                                   \
    float v0 = bf2f((U).x), v1 = bf2f((U).y);                  \
    float v2 = bf2f((U).z), v3 = bf2f((U).w);                  \
    float t =      at.x * fabsf(v0 + xr.x);                    \
    t = fmaf(at.y, fabsf(v1 + xr.y), t);                       \
    t = fmaf(at.z, fabsf(v2 + xr.z), t);                       \
    t = fmaf(at.w, fabsf(v3 + xr.w), t);                       \
    float p = expclamp(sum8(t) + (DLV) + dRn);                 \
    p = ((II) < end) ? p : 0.f;                                \
    d += p;                                                    \
    s.x = fmaf(p, v0, s.x); s.y = fmaf(p, v1, s.y);            \
    s.z = fmaf(p, v2, s.z); s.w = fmaf(p, v3, s.w); }

    if (beg < end) {
        ushort4 cu0, cu1, cu2, cu3;
        float cd0, cd1, cd2, cd3;
        GL01(beg, cu0, cu1, cu2, cu3, cd0, cd1, cd2, cd3)
        for (int i = beg; i < end; i += 8) {
            ushort4 nu0, nu1, nu2, nu3;
            float nd0, nd1, nd2, nd3;
            GL01(i + 8, nu0, nu1, nu2, nu3, nd0, nd1, nd2, nd3)
            EDGE01(cu0, cd0, i + half)
            EDGE01(cu1, cd1, i + 2 + half)
            EDGE01(cu2, cd2, i + 4 + half)
            EDGE01(cu3, cd3, i + 6 + half)
            cu0 = nu0; cu1 = nu1; cu2 = nu2; cu3 = nu3;
            cd0 = nd0; cd1 = nd1; cd2 = nd2; cd3 = nd3;
        }
    }
#undef GL01
#undef EDGE01

    d   += __shfl_xor(d, 32);
    s.x += __shfl_xor(s.x, 32);
    s.y += __shfl_xor(s.y, 32);
    s.z += __shfl_xor(s.z, 32);
    s.w += __shfl_xor(s.w, 32);

    if (half == 0) {
        float inv = (d > 0.f) ? 1.f / d : 0.f;
        float4 rv = RES4[(uint)n * 32u + j];
        float4 bv = ((const float4*)bias)[j];
        float o0 = fmaf(s.x, inv, rv.x + bv.x);
        float o1 = fmaf(s.y, inv, rv.y + bv.y);
        float o2 = fmaf(s.z, inv, rv.z + bv.z);
        float o3 = fmaf(s.w, inv, rv.w + bv.w);
        o0 = o0 > 0.f ? o0 : __expf(o0) - 1.f;   // ELU
        o1 = o1 > 0.f ? o1 : __expf(o1) - 1.f;
        o2 = o2 > 0.f ? o2 : __expf(o2) - 1.f;
        o3 = o3 > 0.f ? o3 : __expf(o3) - 1.f;
        ushort4 h, l;
        h.x = f2bf(o0); l.x = f2bf(o0 - bf2f(h.x));
        h.y = f2bf(o1); l.y = f2bf(o1 - bf2f(h.y));
        h.z = f2bf(o2); l.z = f2bf(o2 - bf2f(h.z));
        h.w = f2bf(o3); l.w = f2bf(o3 - bf2f(h.w));
        *(ushort4*)(Hh + (uint)n * 128u + 4u * j) = h;
        *(ushort4*)(Hl + (uint)n * 128u + 4u * j) = l;
    }
}

// ---------------------------------------------------------------------------
// Aggregation layer 2 — F=64, H=1, 16 lanes/edge, 4 channels/lane,
// 8 edges/iter (2 quad-packets), 2-stage pipeline, unified masked loop.
// ---------------------------------------------------------------------------
__global__ __launch_bounds__(256) void k_agg2(const ushort* __restrict__ XLb,
                                              const float4* __restrict__ XR4,
                                              const float* __restrict__ att,
                                              const float* __restrict__ bias,
                                              const float* __restrict__ DL,
                                              const float* __restrict__ DR,
                                              const int* __restrict__ rowptr,
                                              const int* __restrict__ csrc,
                                              float* __restrict__ OUT) {
    const int lane = threadIdx.x & 63;
    const int wid = threadIdx.x >> 6;
    const int n = blockIdx.x * 4 + wid;
    if (n >= NN) return;
    const int beg = rowptr[n];
    const int end = rowptr[n + 1];
    const int e1 = end - 1;
    const int q = lane >> 4;
    const uint jj = lane & 15;

    const float4 xr = XR4[(uint)n * 16u + jj];
    float4 at = ((const float4*)att)[jj];
    at.x *= 0.4f; at.y *= 0.4f; at.z *= 0.4f; at.w *= 0.4f;
    const float dRn = DR[n];
    float4 s = {0.f, 0.f, 0.f, 0.f};
    float d = 0.f;

#define GL2(I, U0, U1, D0, D1) {                               \
    uint sa = (uint)csrc[min((I) + q, e1)];                    \
    uint sb = (uint)csrc[min((I) + 4 + q, e1)];                \
    U0 = *(const ushort4*)(XLb + sa * 64u + 4u * jj);          \
    U1 = *(const ushort4*)(XLb + sb * 64u + 4u * jj);          \
    D0 = DL[sa];                                               \
    D1 = DL[sb]; }

#define EDGE2(U, DLV, II) {                                    \
    float v0 = bf2f((U).x), v1 = bf2f((U).y);                  \
    float v2 = bf2f((U).z), v3 = bf2f((U).w);                  \
    float t =      at.x * fabsf(v0 + xr.x);                    \
    t = fmaf(at.y, fabsf(v1 + xr.y), t);                       \
    t = fmaf(at.z, fabsf(v2 + xr.z), t);                       \
    t = fmaf(at.w, fabsf(v3 + xr.w), t);                       \
    float p = expclamp(sum16(t) + (DLV) + dRn);                \
    p = ((II) < end) ? p : 0.f;                                \
    d += p;                                                    \
    s.x = fmaf(p, v0, s.x); s.y = fmaf(p, v1, s.y);            \
    s.z = fmaf(p, v2, s.z); s.w = fmaf(p, v3, s.w); }

    if (beg < end) {
        ushort4 cu0, cu1;
        float cd0, cd1;
        GL2(beg, cu0, cu1, cd0, cd1)
        for (int i = beg; i < end; i += 8) {
            ushort4 nu0, nu1;
            float nd0, nd1;
            GL2(i + 8, nu0, nu1, nd0, nd1)
            EDGE2(cu0, cd0, i + q)
            EDGE2(cu1, cd1, i + 4 + q)
            cu0 = nu0; cu1 = nu1;
            cd0 = nd0; cd1 = nd1;
        }
    }
#undef GL2
#undef EDGE2

    d   += __shfl_xor(d, 16);   d   += __shfl_xor(d, 32);
    s.x += __shfl_xor(s.x, 16); s.x += __shfl_xor(s.x, 32);
    s.y += __shfl_xor(s.y, 16); s.y += __shfl_xor(s.y, 32);
    s.z += __shfl_xor(s.z, 16); s.z += __shfl_xor(s.z, 32);
    s.w += __shfl_xor(s.w, 16); s.w += __shfl_xor(s.w, 32);

    if (lane < 16) {
        float inv = (d > 0.f) ? 1.f / d : 0.f;
        float4 bv = ((const float4*)bias)[jj];
        float4 o;
        o.x = fmaf(s.x, inv, bv.x);
        o.y = fmaf(s.y, inv, bv.y);
        o.z = fmaf(s.z, inv, bv.z);
        o.w = fmaf(s.w, inv, bv.w);
        *(float4*)(OUT + (uint)n * 64u + 4u * jj) = o;
    }
}

// ---------------------------------------------------------------------------
extern "C" void kernel_launch(void* const* d_in, const int* in_sizes, int n_in,
                              void* d_out, int out_size, void* d_ws, size_t ws_size,
                              hipStream_t stream) {
    const float* x    = (const float*)d_in[0];
    const int*   ei   = (const int*)d_in[1];
    const int*   esrc = ei;
    const int*   edst = ei + EE;

    const float* Wl0 = (const float*)d_in[2];
    const float* bl0 = (const float*)d_in[3];
    const float* Wr0 = (const float*)d_in[4];
    const float* br0 = (const float*)d_in[5];
    const float* at0 = (const float*)d_in[6];
    const float* b0  = (const float*)d_in[7];
    const float* rs0 = (const float*)d_in[8];
    const float* Wl1 = (const float*)d_in[9];
    const float* bl1 = (const float*)d_in[10];
    const float* Wr1 = (const float*)d_in[11];
    const float* br1 = (const float*)d_in[12];
    const float* at1 = (const float*)d_in[13];
    const float* b1  = (const float*)d_in[14];
    const float* rs1 = (const float*)d_in[15];
    const float* Wl2 = (const float*)d_in[16];
    const float* bl2 = (const float*)d_in[17];
    const float* Wr2 = (const float*)d_in[18];
    const float* br2 = (const float*)d_in[19];
    const float* at2 = (const float*)d_in[20];
    const float* b2  = (const float*)d_in[21];

    float* out = (float*)d_out;

    // --- workspace layout ---
    ushort* XLb = (ushort*)d_ws;               // [NN*128] bf16 (gather payload)
    float* XR  = (float*)(XLb + (size_t)NN * 128);    // [NN*128] fp32
    float* RES = XR + (size_t)NN * 128;               // [NN*128] fp32
    ushort* Xh = (ushort*)(RES + (size_t)NN * 128);   // [NN*128] bf16-hi (H)
    ushort* Xl_ = Xh + (size_t)NN * 128;              // [NN*128] bf16-lo (H)
    float* DLarr = (float*)(Xl_ + (size_t)NN * 128);  // [NN*4] fp32 dotL
    float* DRarr = DLarr + (size_t)NN * 4;            // [NN*4] fp32 dotR
    ushort* Wth = (ushort*)(DRarr + (size_t)NN * 4);
    const int wsz[8] = {16384, 16384, 16384, 16384, 16384, 16384, 8192, 8192};
    ushort* th[8]; ushort* tl[8];
    {
        ushort* p = Wth;
        for (int i = 0; i < 8; ++i) { th[i] = p; p += wsz[i]; }
        for (int i = 0; i < 8; ++i) { tl[i] = p; p += wsz[i]; }
    }
    int* bcnt   = (int*)(Wth + 2 * (6 * 16384 + 2 * 8192));  // 256 (memset)
    int* bbase  = bcnt + 256;                  // 256
    int* bcur   = bbase + 256;                 // 256
    int* rowptr = bcur + 256;                  // NN+1
    int* csrc   = rowptr + (NN + 1);           // EE
    uint* ebuf  = (uint*)(csrc + EE);          // EE

    // --- bucketed CSR build (graph identical across layers) ---
    hipMemsetAsync(bcnt, 0, 256 * sizeof(int), stream);
    const int ebk = (EE + EPB - 1) / EPB;      // 196
    k_bktcnt<<<ebk, 256, 0, stream>>>(edst, bcnt);
    k_bscan<<<1, 256, 0, stream>>>(bcnt, bbase, bcur);
    k_bktplace<<<ebk, 256, 0, stream>>>(esrc, edst, bcur, ebuf);
    k_bktfin<<<NBK, 256, 0, stream>>>(ebuf, bbase, bcnt, rowptr, csrc);

    // --- weight conversion ---
    WPack wp;
    const float* Ws[8] = {Wl0, Wr0, rs0, Wl1, Wr1, rs1, Wl2, Wr2};
    const int fouts[8] = {128, 128, 128, 128, 128, 128, 64, 64};
    for (int i = 0; i < 8; ++i) { wp.W[i] = Ws[i]; wp.Th[i] = th[i]; wp.Tl[i] = tl[i]; wp.fout[i] = fouts[i]; }
    k_conv_w<<<dim3(64, 8), 256, 0, stream>>>(wp);

    const int gemm_gx = (NN + 127) / 128;      // 391 row-tiles (128 rows/block)
    const int agg_grid = (NN + 3) / 4;

    // --- Layer 0 (A from fp32 x; 3 weight mats fused; grid.y = t-slice) ---
    k_gemm_fused<128, 3, true, 2><<<dim3(gemm_gx, 4), 512, 0, stream>>>(x, nullptr, nullptr,
        th[0], tl[0], bl0, th[1], tl[1], br0, th[2], tl[2], at0, DLarr, DRarr, XLb, XR, RES);
    k_agg01<<<agg_grid, 256, 0, stream>>>(XLb, (const float4*)XR, (const float4*)RES,
        at0, b0, DLarr, DRarr, rowptr, csrc, Xh, Xl_);

    // --- Layer 1 ---
    k_gemm_fused<128, 3, false, 2><<<dim3(gemm_gx, 4), 512, 0, stream>>>(nullptr, Xh, Xl_,
        th[3], tl[3], bl1, th[4], tl[4], br1, th[5], tl[5], at1, DLarr, DRarr, XLb, XR, RES);
    k_agg01<<<agg_grid, 256, 0, stream>>>(XLb, (const float4*)XR, (const float4*)RES,
        at1, b1, DLarr, DRarr, rowptr, csrc, Xh, Xl_);

    // --- Layer 2 (heads=1, C=64; dot partials via atomics into zeroed DL/DR) ---
    hipMemsetAsync(DLarr, 0, NN * sizeof(float), stream);
    hipMemsetAsync(DRarr, 0, NN * sizeof(float), stream);
    k_gemm_fused<64, 2, false, 2><<<dim3(gemm_gx, 2), 512, 0, stream>>>(nullptr, Xh, Xl_,
        th[6], tl[6], bl2, th[7], tl[7], br2, nullptr, nullptr, at2, DLarr, DRarr, XLb, XR, nullptr);
    k_agg2<<<agg_grid, 256, 0, stream>>>(XLb, (const float4*)XR, at2, b2, DLarr, DRarr, rowptr, csrc, out);
}

// Round 8
// 350.605 us; speedup vs baseline: 1.0582x; 1.0142x over previous
//
#include <hip/hip_runtime.h>
#include <math.h>

// Problem constants (from reference)
#define NN 50000
#define EE 800000
#define NBK 196    // node buckets (256 nodes each): ceil(50000/256)
#define EPB 4096   // edges per pass-A block: ceil(800000/4096) = 196 blocks

typedef short v8s __attribute__((ext_vector_type(8)));
typedef float v4f __attribute__((ext_vector_type(4)));

__device__ __forceinline__ ushort f2bf(float f) {
    uint u = __float_as_uint(f);
    uint r = (u + 0x7fffu + ((u >> 16) & 1u)) >> 16;
    return (ushort)r;
}
__device__ __forceinline__ float bf2f(ushort h) {
    return __uint_as_float(((uint)h) << 16);
}
// leaky_relu(x,0.2) = 0.6x + 0.4|x|
__device__ __forceinline__ float lrelu(float x) {
    return fmaf(0.4f, fabsf(x), 0.6f * x);
}

// async global->LDS, 16B per lane (dest = wave-uniform base + lane*16)
__device__ __forceinline__ void gld_lds16(const void* g, void* l) {
    __builtin_amdgcn_global_load_lds(
        (const __attribute__((address_space(1))) void*)g,
        (__attribute__((address_space(3))) void*)l, 16, 0, 0);
}

// DPP partial reductions (no LDS pipe).
template <int CTRL>
__device__ __forceinline__ float dppadd(float x) {
    int y = __builtin_amdgcn_update_dpp(0, __float_as_int(x), CTRL, 0xf, 0xf, true);
    return x + __int_as_float(y);
}
__device__ __forceinline__ float sum8(float x) {   // sum within aligned 8-groups
    x = dppadd<0xB1>(x);    // quad_perm xor1
    x = dppadd<0x4E>(x);    // quad_perm xor2
    x = dppadd<0x141>(x);   // row_half_mirror
    return x;
}
__device__ __forceinline__ float sum16(float x) {  // sum within aligned 16-rows
    x = sum8(x);
    x = dppadd<0x140>(x);   // row_mirror
    return x;
}
__device__ __forceinline__ float expclamp(float t) {
    return __expf(fminf(fmaxf(t, -60.f), 80.f));
}

// ---------------------------------------------------------------------------
// Bucketed CSR build — no per-node global atomics, no random global writes.
// ---------------------------------------------------------------------------
__global__ __launch_bounds__(256) void k_bktcnt(const int* __restrict__ edst,
                                                int* __restrict__ bcnt) {
    __shared__ int h[NBK];
    int t = threadIdx.x;
    if (t < NBK) h[t] = 0;
    __syncthreads();
    int eb = blockIdx.x * EPB;
    #pragma unroll
    for (int k = 0; k < EPB / 256; ++k) {
        int e = eb + k * 256 + t;
        if (e < EE) atomicAdd(&h[edst[e] >> 8], 1);
    }
    __syncthreads();
    if (t < NBK && h[t]) atomicAdd(&bcnt[t], h[t]);
}

__global__ __launch_bounds__(256) void k_bscan(const int* __restrict__ bcnt,
                                               int* __restrict__ bbase,
                                               int* __restrict__ bcur) {
    __shared__ int sm[256];
    int t = threadIdx.x;
    int v = (t < NBK) ? bcnt[t] : 0;
    sm[t] = v;
    __syncthreads();
    for (int o = 1; o < 256; o <<= 1) {
        int a = (t >= o) ? sm[t - o] : 0;
        __syncthreads();
        sm[t] += a;
        __syncthreads();
    }
    if (t < NBK) { int ex = sm[t] - v; bbase[t] = ex; bcur[t] = ex; }
}

__global__ __launch_bounds__(256) void k_bktplace(const int* __restrict__ esrc,
                                                  const int* __restrict__ edst,
                                                  int* __restrict__ bcur,
                                                  uint* __restrict__ ebuf) {
    __shared__ int h[NBK];
    __shared__ int base[NBK];
    int t = threadIdx.x;
    if (t < NBK) h[t] = 0;
    __syncthreads();
    int eb = blockIdx.x * EPB;
    int pk[EPB / 256];   // (bucket<<16)|local_rank per edge
    #pragma unroll
    for (int k = 0; k < EPB / 256; ++k) {
        int e = eb + k * 256 + t;
        pk[k] = -1;
        if (e < EE) {
            int b = edst[e] >> 8;
            int r = atomicAdd(&h[b], 1);
            pk[k] = (b << 16) | r;
        }
    }
    __syncthreads();
    if (t < NBK && h[t]) base[t] = atomicAdd(&bcur[t], h[t]);
    __syncthreads();
    #pragma unroll
    for (int k = 0; k < EPB / 256; ++k) {
        int e = eb + k * 256 + t;
        if (e < EE) {
            int b = pk[k] >> 16;
            int r = pk[k] & 0xFFFF;
            uint dl = (uint)(edst[e] & 255);
            ebuf[base[b] + r] = (dl << 16) | (uint)esrc[e];
        }
    }
}

// one block per bucket: per-node degree + scan + cursor all in LDS.
__global__ __launch_bounds__(256) void k_bktfin(const uint* __restrict__ ebuf,
                                                const int* __restrict__ bbase,
                                                const int* __restrict__ bcnt,
                                                int* __restrict__ rowptr,
                                                int* __restrict__ csrc) {
    __shared__ int deg[256];
    __shared__ int sm[256];
    __shared__ int cur[256];
    const int b = blockIdx.x;
    const int t = threadIdx.x;
    const int eb = bbase[b];
    const int ec = bcnt[b];
    deg[t] = 0;
    __syncthreads();
    for (int k = t; k < ec; k += 256)
        atomicAdd(&deg[ebuf[eb + k] >> 16], 1);
    __syncthreads();
    int v = deg[t];
    sm[t] = v;
    __syncthreads();
    for (int o = 1; o < 256; o <<= 1) {
        int a = (t >= o) ? sm[t - o] : 0;
        __syncthreads();
        sm[t] += a;
        __syncthreads();
    }
    int node = b * 256 + t;
    if (node < NN) rowptr[node + 1] = eb + sm[t];
    if (node == 0) rowptr[0] = 0;
    cur[t] = sm[t] - v;   // exclusive
    __syncthreads();
    for (int k = t; k < ec; k += 256) {
        uint u = ebuf[eb + k];
        int nl = (int)(u >> 16);
        int r = atomicAdd(&cur[nl], 1);
        csrc[eb + r] = (int)(u & 0xFFFFu);
    }
}

// ---------------------------------------------------------------------------
// Weight conversion: W [128 x FOUT] fp32 -> bf16 hi/lo in MFMA-fragment order.
// ---------------------------------------------------------------------------
struct WPack {
    const float* W[8];
    ushort* Th[8];
    ushort* Tl[8];
    int fout[8];
};

__global__ __launch_bounds__(256) void k_conv_w(WPack p) {
    int wi = blockIdx.y;
    int fout = p.fout[wi];
    int total = 128 * fout;
    int i = blockIdx.x * 256 + threadIdx.x;
    if (i >= total) return;
    int k = i / fout;
    int n = i - k * fout;
    float f = p.W[wi][i];
    ushort h = f2bf(f);
    float lo = f - bf2f(h);
    int t = n >> 4, m = n & 15, c = k >> 5, quad = (k >> 3) & 3, j = k & 7;
    int flat = ((((t * 4 + c) * 4 + quad) * 16 + m) << 3) + j;
    p.Th[wi][flat] = h;
    p.Tl[wi][flat] = f2bf(lo);
}

// ---------------------------------------------------------------------------
// Fused split-bf16 MFMA GEMM + attention-dot epilogue. (round-4 structure:
// 512 thr, B staged in LDS via global_load_lds, blockIdx.y = t-slice)
// O1 (XR) stored bf16 — it only feeds the |xl+xr| logit term; the linear
// logit part rides in fp32 DR.
// ---------------------------------------------------------------------------
template <int FOUT, int NMAT, bool CVT, int TS>
__global__ __launch_bounds__(512) void k_gemm_fused(
    const float* __restrict__ Xf,
    const ushort* __restrict__ Xh, const ushort* __restrict__ Xl,
    const ushort* __restrict__ T0h, const ushort* __restrict__ T0l, const float* __restrict__ B0,
    const ushort* __restrict__ T1h, const ushort* __restrict__ T1l, const float* __restrict__ B1,
    const ushort* __restrict__ T2h, const ushort* __restrict__ T2l,
    const float* __restrict__ ATT, float* __restrict__ DL, float* __restrict__ DR,
    ushort* __restrict__ O0b, ushort* __restrict__ O1b, float* __restrict__ O2)
{
    constexpr int CH = TS * 2048;                 // ushorts per staged chunk
    __shared__ __align__(16) ushort Bs[NMAT * 2 * CH];

    const int tid  = threadIdx.x;
    const int lane = tid & 63;
    const int wid  = tid >> 6;                    // 0..7
    const int m    = lane & 15;
    const int quad = lane >> 4;
    const int row0 = blockIdx.x * 128 + wid * 16;
    const int t0   = blockIdx.y * TS;

    // ---- stage B slice into LDS (one 8KB chunk per table) ----
    {
        const ushort* tbls[6] = {T0h, T0l, T1h, T1l, T2h, T2l};
        #pragma unroll
        for (int k = 0; k < 2 * NMAT; ++k) {
            gld_lds16(tbls[k] + (size_t)t0 * 2048 + (size_t)tid * 8,
                      &Bs[k * CH + tid * 8]);
        }
    }

    // ---- A fragments (per-wave rows) ----
    v8s ah[4], al[4];
    {
        int arow = row0 + m;
        if (arow > NN - 1) arow = NN - 1;
        #pragma unroll
        for (int c = 0; c < 4; ++c) {
            size_t off = (size_t)arow * 128 + c * 32 + quad * 8;
            if constexpr (CVT) {
                float4 f0 = *(const float4*)(Xf + off);
                float4 f1 = *(const float4*)(Xf + off + 4);
                const float fe[8] = {f0.x, f0.y, f0.z, f0.w, f1.x, f1.y, f1.z, f1.w};
                #pragma unroll
                for (int e = 0; e < 8; ++e) {
                    ushort h = f2bf(fe[e]);
                    float lo = fe[e] - bf2f(h);
                    ah[c][e] = (short)h;
                    al[c][e] = (short)(__float_as_uint(lo) >> 16);  // truncate lo
                }
            } else {
                ah[c] = *(const v8s*)(Xh + off);
                al[c] = *(const v8s*)(Xl + off);
            }
        }
    }

    __syncthreads();   // drains global_load_lds (vmcnt) + orders LDS

    float dp0[4] = {0.f, 0.f, 0.f, 0.f};
    float dp1[4] = {0.f, 0.f, 0.f, 0.f};

    #pragma unroll
    for (int tt = 0; tt < TS; ++tt) {
        const int t = t0 + tt;
        v4f a0 = {0.f, 0.f, 0.f, 0.f};
        v4f a1 = {0.f, 0.f, 0.f, 0.f};
        v4f a2 = {0.f, 0.f, 0.f, 0.f};
        #pragma unroll
        for (int c = 0; c < 4; ++c) {
            const int fo = tt * 2048 + (c * 4 + quad) * 128 + m * 8;
            v8s b0h = *(const v8s*)&Bs[0 * CH + fo];
            v8s b0l = *(const v8s*)&Bs[1 * CH + fo];
            v8s b1h = *(const v8s*)&Bs[2 * CH + fo];
            v8s b1l = *(const v8s*)&Bs[3 * CH + fo];
            a0 = __builtin_amdgcn_mfma_f32_16x16x32_bf16(al[c], b0h, a0, 0, 0, 0);
            a1 = __builtin_amdgcn_mfma_f32_16x16x32_bf16(al[c], b1h, a1, 0, 0, 0);
            a0 = __builtin_amdgcn_mfma_f32_16x16x32_bf16(ah[c], b0l, a0, 0, 0, 0);
            a1 = __builtin_amdgcn_mfma_f32_16x16x32_bf16(ah[c], b1l, a1, 0, 0, 0);
            a0 = __builtin_amdgcn_mfma_f32_16x16x32_bf16(ah[c], b0h, a0, 0, 0, 0);
            a1 = __builtin_amdgcn_mfma_f32_16x16x32_bf16(ah[c], b1h, a1, 0, 0, 0);
            if constexpr (NMAT == 3) {
                v8s b2h = *(const v8s*)&Bs[4 * CH + fo];
                v8s b2l = *(const v8s*)&Bs[5 * CH + fo];
                a2 = __builtin_amdgcn_mfma_f32_16x16x32_bf16(al[c], b2h, a2, 0, 0, 0);
                a2 = __builtin_amdgcn_mfma_f32_16x16x32_bf16(ah[c], b2l, a2, 0, 0, 0);
                a2 = __builtin_amdgcn_mfma_f32_16x16x32_bf16(ah[c], b2h, a2, 0, 0, 0);
            }
        }
        const int col = t * 16 + m;
        const float bad0 = B0[col];
        const float bad1 = B1[col];
        const float attc = ATT[col];
        #pragma unroll
        for (int j = 0; j < 4; ++j) {
            float o0v = a0[j] + bad0;
            float o1v = a1[j] + bad1;
            dp0[j] = fmaf(attc, o0v, dp0[j]);
            dp1[j] = fmaf(attc, o1v, dp1[j]);
            int r = row0 + quad * 4 + j;
            if (r < NN) {
                O0b[(size_t)r * FOUT + col] = f2bf(o0v);
                O1b[(size_t)r * FOUT + col] = f2bf(o1v);
                if constexpr (NMAT == 3) O2[(size_t)r * FOUT + col] = a2[j];
            }
        }
        if constexpr (FOUT == 128) {
            if ((t & 1) == 1) {   // head h = t>>1 complete -> reduce + store
                const int h = t >> 1;
                #pragma unroll
                for (int j = 0; j < 4; ++j) {
                    float s0 = sum16(dp0[j]);
                    float s1 = sum16(dp1[j]);
                    int r = row0 + quad * 4 + j;
                    if (m == 0 && r < NN) {
                        DL[(size_t)r * 4 + h] = 0.6f * s0;
                        DR[(size_t)r * 4 + h] = 0.6f * s1;
                    }
                    dp0[j] = 0.f;
                    dp1[j] = 0.f;
                }
            }
        }
    }
    if constexpr (FOUT == 64) {   // head spans all 4 t -> partial, atomic
        #pragma unroll
        for (int j = 0; j < 4; ++j) {
            float s0 = sum16(dp0[j]);
            float s1 = sum16(dp1[j]);
            int r = row0 + quad * 4 + j;
            if (m == 0 && r < NN) {
                atomicAdd(&DL[r], 0.6f * s0);
                atomicAdd(&DR[r], 0.6f * s1);
            }
        }
    }
}

// ---------------------------------------------------------------------------
// Aggregation layers 0/1 — 32 lanes/edge, 4 channels/lane, 2-stage pipeline,
// unified masked loop. XR read as bf16 (logit-only use).
//   logit = sum8(0.4*att_c*|xl_c+xr_c|) + DL[src,h] + DR[n,h]
// ---------------------------------------------------------------------------
__global__ __launch_bounds__(256) void k_agg01(const ushort* __restrict__ XLb,
                                               const ushort* __restrict__ XRb,
                                               const float4* __restrict__ RES4,
                                               const float* __restrict__ att,
                                               const float* __restrict__ bias,
                                               const float* __restrict__ DL,
                                               const float* __restrict__ DR,
                                               const int* __restrict__ rowptr,
                                               const int* __restrict__ csrc,
                                               ushort* __restrict__ Hh,
                                               ushort* __restrict__ Hl) {
    const int lane = threadIdx.x & 63;
    const int wid = threadIdx.x >> 6;
    const int n = blockIdx.x * 4 + wid;
    if (n >= NN) return;
    const int beg = rowptr[n];
    const int end = rowptr[n + 1];
    const int e1 = end - 1;
    const int half = lane >> 5;
    const uint j = lane & 31;
    const uint head = j >> 3;

    float4 xr;
    {
        ushort4 u = *(const ushort4*)(XRb + (uint)n * 128u + 4u * j);
        xr.x = bf2f(u.x); xr.y = bf2f(u.y); xr.z = bf2f(u.z); xr.w = bf2f(u.w);
    }
    float4 at = ((const float4*)att)[j];
    at.x *= 0.4f; at.y *= 0.4f; at.z *= 0.4f; at.w *= 0.4f;
    const float dRn = DR[(uint)n * 4u + head];
    float4 s = {0.f, 0.f, 0.f, 0.f};
    float d = 0.f;

#define GL01(I, U0, U1, U2, U3, D0, D1, D2, D3) {              \
    uint sa = (uint)csrc[min((I) + half, e1)];                 \
    uint sb = (uint)csrc[min((I) + 2 + half, e1)];             \
    uint sc = (uint)csrc[min((I) + 4 + half, e1)];             \
    uint sd = (uint)csrc[min((I) + 6 + half, e1)];             \
    U0 = *(const ushort4*)(XLb + sa * 128u + 4u * j);          \
    U1 = *(const ushort4*)(XLb + sb * 128u + 4u * j);          \
    U2 = *(const ushort4*)(XLb + sc * 128u + 4u * j);          \
    U3 = *(const ushort4*)(XLb + sd * 128u + 4u * j);          \
    D0 = DL[sa * 4u + head];                                   \
    D1 = DL[sb * 4u + head];                                   \
    D2 = DL[sc * 4u + head];                                   \
    D3 = DL[sd * 4u + head]; }

#define EDGE01(U, DLV, II) {                                   \
    float v0 = bf2f((U).x), v1 = bf2f((U).y);                  \
    float v2 = bf2f((U).z), v3 = bf2f((U).w);                  \
    float t =      at.x * fabsf(v0 + xr.x);                    \
    t = fmaf(at.y, fabsf(v1 + xr.y), t);                       \
    t = fmaf(at.z, fabsf(v2 + xr.z), t);                       \
    t = fmaf(at.w, fabsf(v3 + xr.w), t);                       \
    float p = expclamp(sum8(t) + (DLV) + dRn);                 \
    p = ((II) < end) ? p : 0.f;                                \
    d += p;                                                    \
    s.x = fmaf(p, v0, s.x); s.y = fmaf(p, v1, s.y);            \
    s.z = fmaf(p, v2, s.z); s.w = fmaf(p, v3, s.w); }

    if (beg < end) {
        ushort4 cu0, cu1, cu2, cu3;
        float cd0, cd1, cd2, cd3;
        GL01(beg, cu0, cu1, cu2, cu3, cd0, cd1, cd2, cd3)
        for (int i = beg; i < end; i += 8) {
            ushort4 nu0, nu1, nu2, nu3;
            float nd0, nd1, nd2, nd3;
            GL01(i + 8, nu0, nu1, nu2, nu3, nd0, nd1, nd2, nd3)
            EDGE01(cu0, cd0, i + half)
            EDGE01(cu1, cd1, i + 2 + half)
            EDGE01(cu2, cd2, i + 4 + half)
            EDGE01(cu3, cd3, i + 6 + half)
            cu0 = nu0; cu1 = nu1; cu2 = nu2; cu3 = nu3;
            cd0 = nd0; cd1 = nd1; cd2 = nd2; cd3 = nd3;
        }
    }
#undef GL01
#undef EDGE01

    d   += __shfl_xor(d, 32);
    s.x += __shfl_xor(s.x, 32);
    s.y += __shfl_xor(s.y, 32);
    s.z += __shfl_xor(s.z, 32);
    s.w += __shfl_xor(s.w, 32);

    if (half == 0) {
        float inv = (d > 0.f) ? 1.f / d : 0.f;
        float4 rv = RES4[(uint)n * 32u + j];
        float4 bv = ((const float4*)bias)[j];
        float o0 = fmaf(s.x, inv, rv.x + bv.x);
        float o1 = fmaf(s.y, inv, rv.y + bv.y);
        float o2 = fmaf(s.z, inv, rv.z + bv.z);
        float o3 = fmaf(s.w, inv, rv.w + bv.w);
        o0 = o0 > 0.f ? o0 : __expf(o0) - 1.f;   // ELU
        o1 = o1 > 0.f ? o1 : __expf(o1) - 1.f;
        o2 = o2 > 0.f ? o2 : __expf(o2) - 1.f;
        o3 = o3 > 0.f ? o3 : __expf(o3) - 1.f;
        ushort4 h, l;
        h.x = f2bf(o0); l.x = f2bf(o0 - bf2f(h.x));
        h.y = f2bf(o1); l.y = f2bf(o1 - bf2f(h.y));
        h.z = f2bf(o2); l.z = f2bf(o2 - bf2f(h.z));
        h.w = f2bf(o3); l.w = f2bf(o3 - bf2f(h.w));
        *(ushort4*)(Hh + (uint)n * 128u + 4u * j) = h;
        *(ushort4*)(Hl + (uint)n * 128u + 4u * j) = l;
    }
}

// ---------------------------------------------------------------------------
// Aggregation layer 2 — F=64, H=1, 16 lanes/edge, 4 channels/lane,
// 2-stage pipeline, unified masked loop. XR read as bf16.
// ---------------------------------------------------------------------------
__global__ __launch_bounds__(256) void k_agg2(const ushort* __restrict__ XLb,
                                              const ushort* __restrict__ XRb,
                                              const float* __restrict__ att,
                                              const float* __restrict__ bias,
                                              const float* __restrict__ DL,
                                              const float* __restrict__ DR,
                                              const int* __restrict__ rowptr,
                                              const int* __restrict__ csrc,
                                              float* __restrict__ OUT) {
    const int lane = threadIdx.x & 63;
    const int wid = threadIdx.x >> 6;
    const int n = blockIdx.x * 4 + wid;
    if (n >= NN) return;
    const int beg = rowptr[n];
    const int end = rowptr[n + 1];
    const int e1 = end - 1;
    const int q = lane >> 4;
    const uint jj = lane & 15;

    float4 xr;
    {
        ushort4 u = *(const ushort4*)(XRb + (uint)n * 64u + 4u * jj);
        xr.x = bf2f(u.x); xr.y = bf2f(u.y); xr.z = bf2f(u.z); xr.w = bf2f(u.w);
    }
    float4 at = ((const float4*)att)[jj];
    at.x *= 0.4f; at.y *= 0.4f; at.z *= 0.4f; at.w *= 0.4f;
    const float dRn = DR[n];
    float4 s = {0.f, 0.f, 0.f, 0.f};
    float d = 0.f;

#define GL2(I, U0, U1, D0, D1) {                               \
    uint sa = (uint)csrc[min((I) + q, e1)];                    \
    uint sb = (uint)csrc[min((I) + 4 + q, e1)];                \
    U0 = *(const ushort4*)(XLb + sa * 64u + 4u * jj);          \
    U1 = *(const ushort4*)(XLb + sb * 64u + 4u * jj);          \
    D0 = DL[sa];                                               \
    D1 = DL[sb]; }

#define EDGE2(U, DLV, II) {                                    \
    float v0 = bf2f((U).x), v1 = bf2f((U).y);                  \
    float v2 = bf2f((U).z), v3 = bf2f((U).w);                  \
    float t =      at.x * fabsf(v0 + xr.x);                    \
    t = fmaf(at.y, fabsf(v1 + xr.y), t);                       \
    t = fmaf(at.z, fabsf(v2 + xr.z), t);                       \
    t = fmaf(at.w, fabsf(v3 + xr.w), t);                       \
    float p = expclamp(sum16(t) + (DLV) + dRn);                \
    p = ((II) < end) ? p : 0.f;                                \
    d += p;                                                    \
    s.x = fmaf(p, v0, s.x); s.y = fmaf(p, v1, s.y);            \
    s.z = fmaf(p, v2, s.z); s.w = fmaf(p, v3, s.w); }

    if (beg < end) {
        ushort4 cu0, cu1;
        float cd0, cd1;
        GL2(beg, cu0, cu1, cd0, cd1)
        for (int i = beg; i < end; i += 8) {
            ushort4 nu0, nu1;
            float nd0, nd1;
            GL2(i + 8, nu0, nu1, nd0, nd1)
            EDGE2(cu0, cd0, i + q)
            EDGE2(cu1, cd1, i + 4 + q)
            cu0 = nu0; cu1 = nu1;
            cd0 = nd0; cd1 = nd1;
        }
    }
#undef GL2
#undef EDGE2

    d   += __shfl_xor(d, 16);   d   += __shfl_xor(d, 32);
    s.x += __shfl_xor(s.x, 16); s.x += __shfl_xor(s.x, 32);
    s.y += __shfl_xor(s.y, 16); s.y += __shfl_xor(s.y, 32);
    s.z += __shfl_xor(s.z, 16); s.z += __shfl_xor(s.z, 32);
    s.w += __shfl_xor(s.w, 16); s.w += __shfl_xor(s.w, 32);

    if (lane < 16) {
        float inv = (d > 0.f) ? 1.f / d : 0.f;
        float4 bv = ((const float4*)bias)[jj];
        float4 o;
        o.x = fmaf(s.x, inv, bv.x);
        o.y = fmaf(s.y, inv, bv.y);
        o.z = fmaf(s.z, inv, bv.z);
        o.w = fmaf(s.w, inv, bv.w);
        *(float4*)(OUT + (uint)n * 64u + 4u * jj) = o;
    }
}

// ---------------------------------------------------------------------------
extern "C" void kernel_launch(void* const* d_in, const int* in_sizes, int n_in,
                              void* d_out, int out_size, void* d_ws, size_t ws_size,
                              hipStream_t stream) {
    const float* x    = (const float*)d_in[0];
    const int*   ei   = (const int*)d_in[1];
    const int*   esrc = ei;
    const int*   edst = ei + EE;

    const float* Wl0 = (const float*)d_in[2];
    const float* bl0 = (const float*)d_in[3];
    const float* Wr0 = (const float*)d_in[4];
    const float* br0 = (const float*)d_in[5];
    const float* at0 = (const float*)d_in[6];
    const float* b0  = (const float*)d_in[7];
    const float* rs0 = (const float*)d_in[8];
    const float* Wl1 = (const float*)d_in[9];
    const float* bl1 = (const float*)d_in[10];
    const float* Wr1 = (const float*)d_in[11];
    const float* br1 = (const float*)d_in[12];
    const float* at1 = (const float*)d_in[13];
    const float* b1  = (const float*)d_in[14];
    const float* rs1 = (const float*)d_in[15];
    const float* Wl2 = (const float*)d_in[16];
    const float* bl2 = (const float*)d_in[17];
    const float* Wr2 = (const float*)d_in[18];
    const float* br2 = (const float*)d_in[19];
    const float* at2 = (const float*)d_in[20];
    const float* b2  = (const float*)d_in[21];

    float* out = (float*)d_out;

    // --- workspace layout ---
    ushort* XLb = (ushort*)d_ws;               // [NN*128] bf16 (gather payload)
    ushort* XRb = XLb + (size_t)NN * 128;             // [NN*128] bf16 (XR)
    float* RES = (float*)(XRb + (size_t)NN * 128);    // [NN*128] fp32
    ushort* Xh = (ushort*)(RES + (size_t)NN * 128);   // [NN*128] bf16-hi (H)
    ushort* Xl_ = Xh + (size_t)NN * 128;              // [NN*128] bf16-lo (H)
    float* DLarr = (float*)(Xl_ + (size_t)NN * 128);  // [NN*4] fp32 dotL
    float* DRarr = DLarr + (size_t)NN * 4;            // [NN*4] fp32 dotR
    ushort* Wth = (ushort*)(DRarr + (size_t)NN * 4);
    const int wsz[8] = {16384, 16384, 16384, 16384, 16384, 16384, 8192, 8192};
    ushort* th[8]; ushort* tl[8];
    {
        ushort* p = Wth;
        for (int i = 0; i < 8; ++i) { th[i] = p; p += wsz[i]; }
        for (int i = 0; i < 8; ++i) { tl[i] = p; p += wsz[i]; }
    }
    int* bcnt   = (int*)(Wth + 2 * (6 * 16384 + 2 * 8192));  // 256 (memset)
    int* bbase  = bcnt + 256;                  // 256
    int* bcur   = bbase + 256;                 // 256
    int* rowptr = bcur + 256;                  // NN+1
    int* csrc   = rowptr + (NN + 1);           // EE
    uint* ebuf  = (uint*)(csrc + EE);          // EE

    // --- bucketed CSR build (graph identical across layers) ---
    hipMemsetAsync(bcnt, 0, 256 * sizeof(int), stream);
    const int ebk = (EE + EPB - 1) / EPB;      // 196
    k_bktcnt<<<ebk, 256, 0, stream>>>(edst, bcnt);
    k_bscan<<<1, 256, 0, stream>>>(bcnt, bbase, bcur);
    k_bktplace<<<ebk, 256, 0, stream>>>(esrc, edst, bcur, ebuf);
    k_bktfin<<<NBK, 256, 0, stream>>>(ebuf, bbase, bcnt, rowptr, csrc);

    // --- weight conversion ---
    WPack wp;
    const float* Ws[8] = {Wl0, Wr0, rs0, Wl1, Wr1, rs1, Wl2, Wr2};
    const int fouts[8] = {128, 128, 128, 128, 128, 128, 64, 64};
    for (int i = 0; i < 8; ++i) { wp.W[i] = Ws[i]; wp.Th[i] = th[i]; wp.Tl[i] = tl[i]; wp.fout[i] = fouts[i]; }
    k_conv_w<<<dim3(64, 8), 256, 0, stream>>>(wp);

    const int gemm_gx = (NN + 127) / 128;      // 391 row-tiles (128 rows/block)
    const int agg_grid = (NN + 3) / 4;

    // --- Layer 0 (A from fp32 x; 3 weight mats fused; grid.y = t-slice) ---
    k_gemm_fused<128, 3, true, 2><<<dim3(gemm_gx, 4), 512, 0, stream>>>(x, nullptr, nullptr,
        th[0], tl[0], bl0, th[1], tl[1], br0, th[2], tl[2], at0, DLarr, DRarr, XLb, XRb, RES);
    k_agg01<<<agg_grid, 256, 0, stream>>>(XLb, XRb, (const float4*)RES,
        at0, b0, DLarr, DRarr, rowptr, csrc, Xh, Xl_);

    // --- Layer 1 ---
    k_gemm_fused<128, 3, false, 2><<<dim3(gemm_gx, 4), 512, 0, stream>>>(nullptr, Xh, Xl_,
        th[3], tl[3], bl1, th[4], tl[4], br1, th[5], tl[5], at1, DLarr, DRarr, XLb, XRb, RES);
    k_agg01<<<agg_grid, 256, 0, stream>>>(XLb, XRb, (const float4*)RES,
        at1, b1, DLarr, DRarr, rowptr, csrc, Xh, Xl_);

    // --- Layer 2 (heads=1, C=64; dot partials via atomics into zeroed DL/DR) ---
    hipMemsetAsync(DLarr, 0, NN * sizeof(float), stream);
    hipMemsetAsync(DRarr, 0, NN * sizeof(float), stream);
    k_gemm_fused<64, 2, false, 2><<<dim3(gemm_gx, 2), 512, 0, stream>>>(nullptr, Xh, Xl_,
        th[6], tl[6], bl2, th[7], tl[7], br2, nullptr, nullptr, at2, DLarr, DRarr, XLb, XRb, nullptr);
    k_agg2<<<agg_grid, 256, 0, stream>>>(XLb, XRb, at2, b2, DLarr, DRarr, rowptr, csrc, out);
}